// Round 5
// baseline (740.413 us; speedup 1.0000x reference)
//
#include <hip/hip_runtime.h>
#include <math.h>

namespace {
constexpr int B_=256, T_=256, NT=512;
constexpr int CH=8, NCH=32;

// LDS float offsets
constexpr int O_TCU=0;          // 64
constexpr int O_TCL=64;         // 64
constexpr int O_PM =128;        // 128 state mean
constexpr int O_CU =256;        // 64
constexpr int O_CL =320;        // 64
constexpr int O_CS1=384;        // 64 (ncs split halves)
constexpr int O_CS2=448;        // 64
constexpr int O_MM =512;        // 144: pairs (mu,ml), idx (x+3)*2, x=-3..66
constexpr int O_PA =656;        // 144: pairs (pcu,pcs)
constexpr int O_PB =800;        // 144: pairs (pcl,pcs)
constexpr int O_BND=944;        // [4][64][8] = 2048 (d 0..6 contiguous + 0 pad)
constexpr int O_LG =2992;       // 16 logits (slot15 = -3e38)
constexpr int O_OBS=3008;       // [8][64]
constexpr int O_OV =3520;       // [8][64]
constexpr int O_ACT=4032;       // [8][32]
constexpr int O_H  =4288;       // [8][64]
constexpr int O_CT =4800;       // [8][128]
constexpr int O_END=5824;       // 23296 B

constexpr long long NBT = (long long)B_*T_;
constexpr long long OO1 = NBT*128;          // pcu
constexpr long long OO2 = OO1 + NBT*64;     // pcl
constexpr long long OO3 = OO2 + NBT*64;     // pcs
constexpr long long OO4 = OO3 + NBT*64;     // npm
constexpr long long OO5 = OO4 + NBT*128;    // ncu
constexpr long long OO6 = OO5 + NBT*64;     // ncl
constexpr long long OO7 = OO6 + NBT*64;     // ncs
}

// barrier that flushes only LDS (lgkmcnt), NOT the global-store queue (vmcnt)
__device__ __forceinline__ void bar_lds() {
    asm volatile("s_waitcnt lgkmcnt(0)\n\ts_barrier" ::: "memory");
}

template <int CTRL>
__device__ __forceinline__ float dpp_add(float x) {
    int v = __builtin_amdgcn_update_dpp(0, __float_as_int(x), CTRL, 0xf, 0xf, false);
    return x + __int_as_float(v);
}
__device__ __forceinline__ float wave_red64(float x) {
    x = dpp_add<0xB1>(x);    // quad_perm xor1
    x = dpp_add<0x4E>(x);    // quad_perm xor2
    x = dpp_add<0x124>(x);   // row_ror:4
    x = dpp_add<0x128>(x);   // row_ror:8 -> row16 sums
    float a = __int_as_float(__builtin_amdgcn_readlane(__float_as_int(x), 16));
    float b = __int_as_float(__builtin_amdgcn_readlane(__float_as_int(x), 32));
    float c = __int_as_float(__builtin_amdgcn_readlane(__float_as_int(x), 48));
    return x + a + b + c;
}

__global__ __launch_bounds__(NT, 2)
void rkn_scan_kernel(const float* __restrict__ g_obs, const float* __restrict__ g_ovar,
                     const float* __restrict__ g_act, const float* __restrict__ g_im,
                     const float* __restrict__ g_icov, const float* __restrict__ g_cw,
                     const float* __restrict__ g_cb, const float* __restrict__ g_w1,
                     const float* __restrict__ g_b1, const float* __restrict__ g_w2,
                     const float* __restrict__ g_b2, const float* __restrict__ g_tmb,
                     const float* __restrict__ g_tcu, const float* __restrict__ g_tcl,
                     const int* __restrict__ g_valid, float* __restrict__ out)
{
    __shared__ __align__(16) float sm[O_END];
    __shared__ int s_val[CH];

    const int t = threadIdx.x;
    const int b = blockIdx.x;
    const int f = t >> 6;         // wave 0..7
    const int i = t & 63;
    const int m = f >> 1;         // matrix 0:A 1:B 2:C 3:D (blend ownership)
    const int oddw = f & 1;       // even: d0..3, odd: d4..6

    // ---------------- prologue ----------------
    if (t < 64) {
        float x = g_tcu[t]; sm[O_TCU+t] = (x >= 0.f) ? x + 1.f : __expf(x);
        float y = g_tcl[t]; sm[O_TCL+t] = (y >= 0.f) ? y + 1.f : __expf(y);
        sm[O_CU+t]  = g_icov[0*B_*64 + b*64 + t];
        sm[O_CL+t]  = g_icov[1*B_*64 + b*64 + t];
        sm[O_CS1+t] = g_icov[2*B_*64 + b*64 + t];
        sm[O_CS2+t] = 0.f;
    }
    if (t < 128) sm[O_PM+t] = g_im[b*128 + t];
    if (t < 432) sm[O_MM+t] = 0.f;          // zero MM/PA/PB incl pads
    if (t == 0)  sm[O_LG+15] = -3.0e38f;

    // MLP weight columns in registers
    float w1c[32], b1r = 0.f;
    if (i < 60) {
        b1r = g_b1[i];
        #pragma unroll
        for (int a = 0; a < 32; ++a) w1c[a] = g_w1[a*60 + i];
    } else {
        #pragma unroll
        for (int a = 0; a < 32; ++a) w1c[a] = 0.f;
    }
    const int ii2 = t & 127;
    float w2c[60];
    #pragma unroll
    for (int j = 0; j < 60; ++j) w2c[j] = g_w2[j*128 + ii2];
    const float b2r = g_b2[ii2];

    // coeff_w columns for this wave's (up to) 2 logits
    const int k0 = 2*f, k1 = 2*f + 1;
    float cwa0 = g_cw[i*15 + k0], cwb0 = g_cw[(64+i)*15 + k0];
    float cb0q = g_cb[k0] * (1.f/64.f);
    float cwa1 = 0.f, cwb1 = 0.f, cb1q = 0.f;
    if (k1 < 15) {
        cwa1 = g_cw[i*15 + k1]; cwb1 = g_cw[(64+i)*15 + k1];
        cb1q = g_cb[k1] * (1.f/64.f);
    }

    // banded basis: this wave's matrix m, d-range [d0, d0+nd)
    const int d0 = oddw ? 4 : 0;
    float bas[15][4];
    #pragma unroll
    for (int k = 0; k < 15; ++k) {
        #pragma unroll
        for (int dd = 0; dd < 4; ++dd) {
            int d = d0 + dd;
            int j = i - 3 + d;
            bas[k][dd] = (d < 7 && j >= 0 && j < 64)
                ? g_tmb[(((long long)m*15 + k)*64 + i)*64 + j] : 0.f;
        }
    }

    const float* pobs = g_obs  + (size_t)b*T_*64;
    const float* pov  = g_ovar + (size_t)b*T_*64;
    const float* pact = g_act  + (size_t)b*T_*32;
    const int*   pval = g_valid + (size_t)b*T_;
    const size_t bt0  = (size_t)b*T_;

    // prefetch chunk 0
    float4 pfA = {0,0,0,0};
    int vpf = 0;
    if (t < 128)                  pfA = *(const float4*)(pobs + t*4);
    else if (t < 256)             pfA = *(const float4*)(pov + (t-128)*4);
    else if (t < 320)             pfA = *(const float4*)(pact + (t-256)*4);
    else if (t < 328)             vpf = pval[t-320];

    #pragma unroll 1
    for (int c = 0; c < NCH; ++c) {
        // stage chunk c
        if (t < 128)        *(float4*)&sm[O_OBS + t*4] = pfA;
        else if (t < 256)   *(float4*)&sm[O_OV  + (t-128)*4] = pfA;
        else if (t < 320)   *(float4*)&sm[O_ACT + (t-256)*4] = pfA;
        else if (t < 328)   s_val[t-320] = vpf;
        bar_lds();

        // issue prefetch for chunk c+1
        if (c + 1 < NCH) {
            const int co = (c+1)*CH;
            if (t < 128)        pfA = *(const float4*)(pobs + co*64 + t*4);
            else if (t < 256)   pfA = *(const float4*)(pov  + co*64 + (t-128)*4);
            else if (t < 320)   pfA = *(const float4*)(pact + co*32 + (t-256)*4);
            else if (t < 328)   vpf = pval[co + t-320];
        }

        // MLP burst 1: h[s][j], s = wave id (act reads broadcast per wave)
        if (i < 60) {
            float acc = b1r;
            #pragma unroll
            for (int a = 0; a < 32; ++a) acc += sm[O_ACT + f*32 + a] * w1c[a];
            sm[O_H + f*64 + i] = fmaxf(acc, 0.f);
        }
        bar_lds();

        // MLP burst 2: ctrl[s][ii] (h reads broadcast per wave)
        #pragma unroll
        for (int r = 0; r < 2; ++r) {
            int s2 = (t >> 7) + r*4;
            float acc = b2r;
            #pragma unroll
            for (int j = 0; j < 60; ++j) acc += sm[O_H + s2*64 + j] * w2c[j];
            sm[O_CT + s2*128 + ii2] = acc;
        }
        // no barrier needed: O_CT consumed in P3, after bar1+bar2

        // ================= 8 scan steps =================
        #pragma unroll 1
        for (int s = 0; s < CH; ++s) {
            const int tt = c*CH + s;
            const size_t bt = bt0 + tt;

            // --- P1: read state, deferred prev-step stores, Kalman update, logits ---
            float pmu = sm[O_PM+i], pml = sm[O_PM+64+i];
            float cuv = sm[O_CU+i], clv = sm[O_CL+i];
            float csv = sm[O_CS1+i] + sm[O_CS2+i];
            float ob  = sm[O_OBS + s*64 + i], ovv = sm[O_OV + s*64 + i];
            const int vld = s_val[s];

            if (tt > 0) {
                const size_t bp = bt - 1;
                if (f == 3)      { out[OO4 + bp*128 + i] = pmu; out[OO4 + bp*128 + 64 + i] = pml; }
                else if (f == 5) { out[OO5 + bp*64 + i] = cuv;  out[OO6 + bp*64 + i] = clv;
                                   out[OO7 + bp*64 + i] = csv; }
            }

            float inv = 1.f/(cuv + ovv);
            float qu = cuv*inv, ql = csv*inv;
            float res = ob - pmu;
            float covf = 1.f - qu;
            float pu  = vld ? pmu + qu*res : pmu;
            float pl  = vld ? pml + ql*res : pml;
            float pcu = vld ? covf*cuv     : cuv;
            float pcl = vld ? clv - ql*csv : clv;
            float pcs = vld ? covf*csv     : csv;

            if (f == 0)      { float2 v = {pu, pl};   *(float2*)&sm[O_MM + (i+3)*2] = v; }
            else if (f == 2) { float2 v = {pcu, pcs}; *(float2*)&sm[O_PA + (i+3)*2] = v; }
            else if (f == 4) { float2 v = {pcl, pcs}; *(float2*)&sm[O_PB + (i+3)*2] = v; }

            float p0 = cb0q + pu*cwa0 + pl*cwb0;
            float p1 = cb1q + pu*cwa1 + pl*cwb1;
            p0 = wave_red64(p0); p1 = wave_red64(p1);
            if (i == 0) {
                sm[O_LG + k0] = p0;
                if (k1 < 15) sm[O_LG + k1] = p1;
            }
            bar_lds();   // b1

            // --- P2: out-stores (w3/w5), softmax, blend, band write ---
            if (f == 3)      { out[bt*128 + i] = pu; out[bt*128 + 64 + i] = pl; }
            else if (f == 5) { out[OO1 + bt*64 + i] = pcu; out[OO2 + bt*64 + i] = pcl;
                               out[OO3 + bt*64 + i] = pcs; }

            float4 L0 = *(const float4*)&sm[O_LG+0];
            float4 L1 = *(const float4*)&sm[O_LG+4];
            float4 L2 = *(const float4*)&sm[O_LG+8];
            float4 L3 = *(const float4*)&sm[O_LG+12];
            float lgv[15] = {L0.x,L0.y,L0.z,L0.w, L1.x,L1.y,L1.z,L1.w,
                             L2.x,L2.y,L2.z,L2.w, L3.x,L3.y,L3.z};
            float mx = lgv[0];
            #pragma unroll
            for (int k = 1; k < 15; ++k) mx = fmaxf(mx, lgv[k]);
            float ssum = 0.f;
            #pragma unroll
            for (int k = 0; k < 15; ++k) { lgv[k] = __expf(lgv[k]-mx); ssum += lgv[k]; }
            float isv = 1.f/ssum;

            float bnd[4] = {0.f,0.f,0.f,0.f};
            #pragma unroll
            for (int k = 0; k < 15; ++k) {
                #pragma unroll
                for (int dd = 0; dd < 4; ++dd) bnd[dd] += lgv[k]*bas[k][dd];
            }
            #pragma unroll
            for (int dd = 0; dd < 4; ++dd) bnd[dd] *= isv;
            if (!oddw) {
                if (f == 0 || f == 6) bnd[3] += 1.f;  // +eye diag (d==3), A and D
                float4 v = {bnd[0],bnd[1],bnd[2],bnd[3]};
                *(float4*)&sm[O_BND + (m*64+i)*8] = v;
            } else {
                float4 v = {bnd[0],bnd[1],bnd[2],0.f};
                *(float4*)&sm[O_BND + (m*64+i)*8 + 4] = v;
            }
            bar_lds();   // b2

            // --- P3: role-split propagation ---
            if (f == 0) {
                float4 a03 = *(const float4*)&sm[O_BND + (0*64+i)*8];
                float4 a46 = *(const float4*)&sm[O_BND + (0*64+i)*8 + 4];
                float4 b03 = *(const float4*)&sm[O_BND + (1*64+i)*8];
                float4 b46 = *(const float4*)&sm[O_BND + (1*64+i)*8 + 4];
                float A[7]={a03.x,a03.y,a03.z,a03.w,a46.x,a46.y,a46.z};
                float Bb[7]={b03.x,b03.y,b03.z,b03.w,b46.x,b46.y,b46.z};
                float acc = sm[O_CT + s*128 + i];
                #pragma unroll
                for (int d = 0; d < 7; ++d) {
                    float2 mm = *(const float2*)&sm[O_MM + (i+d)*2];
                    acc += A[d]*mm.x + Bb[d]*mm.y;
                }
                sm[O_PM+i] = acc;
            } else if (f == 1) {
                float4 c03 = *(const float4*)&sm[O_BND + (2*64+i)*8];
                float4 c46 = *(const float4*)&sm[O_BND + (2*64+i)*8 + 4];
                float4 d03 = *(const float4*)&sm[O_BND + (3*64+i)*8];
                float4 d46 = *(const float4*)&sm[O_BND + (3*64+i)*8 + 4];
                float Cv[7]={c03.x,c03.y,c03.z,c03.w,c46.x,c46.y,c46.z};
                float Dv[7]={d03.x,d03.y,d03.z,d03.w,d46.x,d46.y,d46.z};
                float acc = sm[O_CT + s*128 + 64 + i];
                #pragma unroll
                for (int d = 0; d < 7; ++d) {
                    float2 mm = *(const float2*)&sm[O_MM + (i+d)*2];
                    acc += Cv[d]*mm.x + Dv[d]*mm.y;
                }
                sm[O_PM+64+i] = acc;
            } else if (f == 2) {
                float4 a03 = *(const float4*)&sm[O_BND + (0*64+i)*8];
                float4 a46 = *(const float4*)&sm[O_BND + (0*64+i)*8 + 4];
                float4 b03 = *(const float4*)&sm[O_BND + (1*64+i)*8];
                float4 b46 = *(const float4*)&sm[O_BND + (1*64+i)*8 + 4];
                float A[7]={a03.x,a03.y,a03.z,a03.w,a46.x,a46.y,a46.z};
                float Bb[7]={b03.x,b03.y,b03.z,b03.w,b46.x,b46.y,b46.z};
                float acc = sm[O_TCU+i];
                #pragma unroll
                for (int d = 0; d < 7; ++d) {
                    float2 pa = *(const float2*)&sm[O_PA + (i+d)*2];
                    float pclv = sm[O_PB + (i+d)*2];
                    acc += A[d]*A[d]*pa.x + 2.f*A[d]*Bb[d]*pa.y + Bb[d]*Bb[d]*pclv;
                }
                sm[O_CU+i] = acc;
            } else if (f == 4) {
                float4 c03 = *(const float4*)&sm[O_BND + (2*64+i)*8];
                float4 c46 = *(const float4*)&sm[O_BND + (2*64+i)*8 + 4];
                float4 d03 = *(const float4*)&sm[O_BND + (3*64+i)*8];
                float4 d46 = *(const float4*)&sm[O_BND + (3*64+i)*8 + 4];
                float Cv[7]={c03.x,c03.y,c03.z,c03.w,c46.x,c46.y,c46.z};
                float Dv[7]={d03.x,d03.y,d03.z,d03.w,d46.x,d46.y,d46.z};
                float acc = sm[O_TCL+i];
                #pragma unroll
                for (int d = 0; d < 7; ++d) {
                    float2 pa = *(const float2*)&sm[O_PA + (i+d)*2];
                    float pclv = sm[O_PB + (i+d)*2];
                    acc += Cv[d]*Cv[d]*pa.x + 2.f*Cv[d]*Dv[d]*pa.y + Dv[d]*Dv[d]*pclv;
                }
                sm[O_CL+i] = acc;
            } else if (f == 6) {
                float4 a03 = *(const float4*)&sm[O_BND + (0*64+i)*8];
                float4 a46 = *(const float4*)&sm[O_BND + (0*64+i)*8 + 4];
                float4 c03 = *(const float4*)&sm[O_BND + (2*64+i)*8];
                float4 c46 = *(const float4*)&sm[O_BND + (2*64+i)*8 + 4];
                float4 d03 = *(const float4*)&sm[O_BND + (3*64+i)*8];
                float4 d46 = *(const float4*)&sm[O_BND + (3*64+i)*8 + 4];
                float A[7]={a03.x,a03.y,a03.z,a03.w,a46.x,a46.y,a46.z};
                float Cv[7]={c03.x,c03.y,c03.z,c03.w,c46.x,c46.y,c46.z};
                float Dv[7]={d03.x,d03.y,d03.z,d03.w,d46.x,d46.y,d46.z};
                float acc = 0.f;
                #pragma unroll
                for (int d = 0; d < 7; ++d) {
                    float2 pa = *(const float2*)&sm[O_PA + (i+d)*2];
                    acc += A[d]*(Cv[d]*pa.x + Dv[d]*pa.y);
                }
                sm[O_CS1+i] = acc;
            } else if (f == 7) {
                float4 b03 = *(const float4*)&sm[O_BND + (1*64+i)*8];
                float4 b46 = *(const float4*)&sm[O_BND + (1*64+i)*8 + 4];
                float4 c03 = *(const float4*)&sm[O_BND + (2*64+i)*8];
                float4 c46 = *(const float4*)&sm[O_BND + (2*64+i)*8 + 4];
                float4 d03 = *(const float4*)&sm[O_BND + (3*64+i)*8];
                float4 d46 = *(const float4*)&sm[O_BND + (3*64+i)*8 + 4];
                float Bb[7]={b03.x,b03.y,b03.z,b03.w,b46.x,b46.y,b46.z};
                float Cv[7]={c03.x,c03.y,c03.z,c03.w,c46.x,c46.y,c46.z};
                float Dv[7]={d03.x,d03.y,d03.z,d03.w,d46.x,d46.y,d46.z};
                float acc = 0.f;
                #pragma unroll
                for (int d = 0; d < 7; ++d) {
                    float2 pb = *(const float2*)&sm[O_PB + (i+d)*2];
                    acc += Bb[d]*(Cv[d]*pb.y + Dv[d]*pb.x);
                }
                sm[O_CS2+i] = acc;
            }
            bar_lds();   // b3
        }
    }

    // epilogue: deferred stores of step T-1
    {
        const size_t bp = bt0 + (T_-1);
        if (f == 3) {
            out[OO4 + bp*128 + i]      = sm[O_PM+i];
            out[OO4 + bp*128 + 64 + i] = sm[O_PM+64+i];
        } else if (f == 5) {
            out[OO5 + bp*64 + i] = sm[O_CU+i];
            out[OO6 + bp*64 + i] = sm[O_CL+i];
            out[OO7 + bp*64 + i] = sm[O_CS1+i] + sm[O_CS2+i];
        }
    }
}

extern "C" void kernel_launch(void* const* d_in, const int* in_sizes, int n_in,
                              void* d_out, int out_size, void* d_ws, size_t ws_size,
                              hipStream_t stream) {
    (void)in_sizes; (void)n_in; (void)d_ws; (void)ws_size; (void)out_size;
    rkn_scan_kernel<<<B_, NT, 0, stream>>>(
        (const float*)d_in[0],  (const float*)d_in[1],  (const float*)d_in[2],
        (const float*)d_in[3],  (const float*)d_in[4],  (const float*)d_in[5],
        (const float*)d_in[6],  (const float*)d_in[7],  (const float*)d_in[8],
        (const float*)d_in[9],  (const float*)d_in[10], (const float*)d_in[11],
        (const float*)d_in[12], (const float*)d_in[13], (const int*)d_in[14],
        (float*)d_out);
}

// Round 6
// 693.287 us; speedup vs baseline: 1.0680x; 1.0680x over previous
//
#include <hip/hip_runtime.h>
#include <math.h>

namespace {
constexpr int B_=256, T_=256, NT=512;
constexpr int CH=8, NCH=32;

// LDS float offsets (conflict-free layouts)
constexpr int O_TCU =0;            // 64
constexpr int O_TCL =64;           // 64
constexpr int O_PM  =128;          // 128 state mean
constexpr int O_CU  =256;          // 64
constexpr int O_CL  =320;          // 64
constexpr int O_CS1 =384;          // 64 (ncs halves)
constexpr int O_CS2 =448;          // 64
constexpr int O_MU  =512;          // 72 padded (idx +3)
constexpr int O_ML  =584;          // 72
constexpr int O_PCU =656;          // 72
constexpr int O_PCL =728;          // 72
constexpr int O_PCS =800;          // 72  (ends 872, 16B aligned)
constexpr int O_BNDL=872;          // [4][64][4] = 1024, lane-stride 16B
constexpr int O_BNDH=1896;         // [4][64][4] = 1024
constexpr int O_LG  =2920;         // 16 logits (slot15 = -inf)
constexpr int O_OBS =2936;         // [8][64]
constexpr int O_OV  =3448;         // [8][64]
constexpr int O_ACT =3960;         // [8][32]
constexpr int O_H   =4216;         // [8][64]
constexpr int O_CT  =4728;         // [8][128]
constexpr int O_END =5752;         // 23008 B

constexpr long long NBT = (long long)B_*T_;
constexpr long long OO1 = NBT*128;          // pcu
constexpr long long OO2 = OO1 + NBT*64;     // pcl
constexpr long long OO3 = OO2 + NBT*64;     // pcs
constexpr long long OO4 = OO3 + NBT*64;     // npm
constexpr long long OO5 = OO4 + NBT*128;    // ncu
constexpr long long OO6 = OO5 + NBT*64;     // ncl
constexpr long long OO7 = OO6 + NBT*64;     // ncs
}

// barrier flushing only LDS (lgkmcnt), NOT the global-store queue (vmcnt)
__device__ __forceinline__ void bar_lds() {
    asm volatile("s_waitcnt lgkmcnt(0)\n\ts_barrier" ::: "memory");
}

template <int CTRL>
__device__ __forceinline__ float dpp_add(float x) {
    int v = __builtin_amdgcn_update_dpp(0, __float_as_int(x), CTRL, 0xf, 0xf, false);
    return x + __int_as_float(v);
}
__device__ __forceinline__ float wave_red64(float x) {
    x = dpp_add<0xB1>(x);    // quad_perm xor1
    x = dpp_add<0x4E>(x);    // quad_perm xor2
    x = dpp_add<0x124>(x);   // row_ror:4
    x = dpp_add<0x128>(x);   // row_ror:8 -> row16 sums
    float a = __int_as_float(__builtin_amdgcn_readlane(__float_as_int(x), 16));
    float b = __int_as_float(__builtin_amdgcn_readlane(__float_as_int(x), 32));
    float c = __int_as_float(__builtin_amdgcn_readlane(__float_as_int(x), 48));
    return x + a + b + c;
}

__global__ __launch_bounds__(NT, 2)
void rkn_scan_kernel(const float* __restrict__ g_obs, const float* __restrict__ g_ovar,
                     const float* __restrict__ g_act, const float* __restrict__ g_im,
                     const float* __restrict__ g_icov, const float* __restrict__ g_cw,
                     const float* __restrict__ g_cb, const float* __restrict__ g_w1,
                     const float* __restrict__ g_b1, const float* __restrict__ g_w2,
                     const float* __restrict__ g_b2, const float* __restrict__ g_tmb,
                     const float* __restrict__ g_tcu, const float* __restrict__ g_tcl,
                     const int* __restrict__ g_valid, float* __restrict__ out)
{
    __shared__ __align__(16) float sm[O_END];
    __shared__ int s_val[CH];

    const int t = threadIdx.x;
    const int b = blockIdx.x;
    const int f = t >> 6;         // wave 0..7
    const int i = t & 63;
    const int m = f >> 1;         // matrix 0:A 1:B 2:C 3:D
    const int oddw = f & 1;       // even: d0..3 (lo), odd: d4..6 (hi)
    constexpr float LOG2E = 1.4426950408889634f;

    // ---------------- prologue ----------------
    if (t < 64) {
        float x = g_tcu[t]; sm[O_TCU+t] = (x >= 0.f) ? x + 1.f : __expf(x);
        float y = g_tcl[t]; sm[O_TCL+t] = (y >= 0.f) ? y + 1.f : __expf(y);
        sm[O_CU+t]  = g_icov[0*B_*64 + b*64 + t];
        sm[O_CL+t]  = g_icov[1*B_*64 + b*64 + t];
        sm[O_CS1+t] = g_icov[2*B_*64 + b*64 + t];
        sm[O_CS2+t] = 0.f;
    }
    if (t < 128) sm[O_PM+t] = g_im[b*128 + t];
    if (t < 360) sm[O_MU+t] = 0.f;          // zero MU..PCS incl pads
    if (t == 0)  sm[O_LG+15] = -3.0e38f;

    // MLP weight columns in registers
    float w1c[32], b1r = 0.f;
    if (i < 60) {
        b1r = g_b1[i];
        #pragma unroll
        for (int a = 0; a < 32; ++a) w1c[a] = g_w1[a*60 + i];
    } else {
        #pragma unroll
        for (int a = 0; a < 32; ++a) w1c[a] = 0.f;
    }
    const int ii2 = t & 127;
    float w2c[60];
    #pragma unroll
    for (int j = 0; j < 60; ++j) w2c[j] = g_w2[j*128 + ii2];
    const float b2r = g_b2[ii2];

    // coeff_w columns (log2e folded for exp2-softmax)
    const int k0 = 2*f, k1 = 2*f + 1;
    float cwa0 = g_cw[i*15 + k0]*LOG2E, cwb0 = g_cw[(64+i)*15 + k0]*LOG2E;
    float cb0q = g_cb[k0] * (LOG2E/64.f);
    float cwa1 = 0.f, cwb1 = 0.f, cb1q = 0.f;
    if (k1 < 15) {
        cwa1 = g_cw[i*15 + k1]*LOG2E; cwb1 = g_cw[(64+i)*15 + k1]*LOG2E;
        cb1q = g_cb[k1] * (LOG2E/64.f);
    }

    // banded basis: matrix m, d-range [d0, d0+4)
    const int d0 = oddw ? 4 : 0;
    float bas[15][4];
    #pragma unroll
    for (int k = 0; k < 15; ++k) {
        #pragma unroll
        for (int dd = 0; dd < 4; ++dd) {
            int d = d0 + dd;
            int j = i - 3 + d;
            bas[k][dd] = (d < 7 && j >= 0 && j < 64)
                ? g_tmb[(((long long)m*15 + k)*64 + i)*64 + j] : 0.f;
        }
    }

    const float* pobs = g_obs  + (size_t)b*T_*64;
    const float* pov  = g_ovar + (size_t)b*T_*64;
    const float* pact = g_act  + (size_t)b*T_*32;
    const int*   pval = g_valid + (size_t)b*T_;
    const size_t bt0  = (size_t)b*T_;

    // incremental output pointers (per-role)
    float* pPU  = out + bt0*128;            // f3 P2: post_mean
    float* pNP  = out + OO4 + (bt0-1)*128;  // f3 P1: npm (prev step)
    float* pP1  = out + OO1 + bt0*64;       // f5 P2: pcu
    float* pP2  = out + OO2 + bt0*64;       // f5 P2: pcl
    float* pP3  = out + OO3 + bt0*64;       // f5 P2: pcs
    float* pCUo = out + OO5 + (bt0-1)*64;   // f5 P1: ncu (prev)
    float* pCLo = out + OO6 + (bt0-1)*64;
    float* pCSo = out + OO7 + (bt0-1)*64;

    // prefetch chunk 0
    float4 pfA = {0,0,0,0};
    int vpf = 0;
    if (t < 128)        pfA = *(const float4*)(pobs + t*4);
    else if (t < 256)   pfA = *(const float4*)(pov + (t-128)*4);
    else if (t < 320)   pfA = *(const float4*)(pact + (t-256)*4);
    else if (t < 328)   vpf = pval[t-320];

    #pragma unroll 1
    for (int c = 0; c < NCH; ++c) {
        // stage chunk c
        if (t < 128)        *(float4*)&sm[O_OBS + t*4] = pfA;
        else if (t < 256)   *(float4*)&sm[O_OV  + (t-128)*4] = pfA;
        else if (t < 320)   *(float4*)&sm[O_ACT + (t-256)*4] = pfA;
        else if (t < 328)   s_val[t-320] = vpf;
        bar_lds();

        // issue prefetch for chunk c+1
        if (c + 1 < NCH) {
            const int co = (c+1)*CH;
            if (t < 128)        pfA = *(const float4*)(pobs + co*64 + t*4);
            else if (t < 256)   pfA = *(const float4*)(pov  + co*64 + (t-128)*4);
            else if (t < 320)   pfA = *(const float4*)(pact + co*32 + (t-256)*4);
            else if (t < 328)   vpf = pval[co + t-320];
        }

        // MLP burst 1: h[f][i] (act reads broadcast per wave)
        if (i < 60) {
            float acc = b1r;
            #pragma unroll
            for (int a = 0; a < 32; ++a) acc += sm[O_ACT + f*32 + a] * w1c[a];
            sm[O_H + f*64 + i] = fmaxf(acc, 0.f);
        }
        bar_lds();

        // MLP burst 2: ctrl[s][ii2] (h reads broadcast per wave)
        #pragma unroll
        for (int r = 0; r < 2; ++r) {
            int s2 = (t >> 7) + r*4;
            float acc = b2r;
            #pragma unroll
            for (int j = 0; j < 60; ++j) acc += sm[O_H + s2*64 + j] * w2c[j];
            sm[O_CT + s2*128 + ii2] = acc;
        }
        // (no barrier: O_CT consumed in P3, ≥2 barriers later)

        // ================= 8 scan steps =================
        #pragma unroll 1
        for (int s = 0; s < CH; ++s) {
            const int tt = c*CH + s;

            // --- P1: state read, deferred prev stores, Kalman, logits ---
            float pmu = sm[O_PM+i], pml = sm[O_PM+64+i];
            float cuv = sm[O_CU+i];
            float clv = (f == 4 || f == 5) ? sm[O_CL+i] : 0.f;
            float csv = sm[O_CS1+i] + sm[O_CS2+i];
            float ob  = sm[O_OBS + s*64 + i], ovv = sm[O_OV + s*64 + i];
            const int vld = s_val[s];

            if (tt > 0) {
                if (f == 3)      { pNP[i] = pmu; pNP[64+i] = pml; }
                else if (f == 5) { pCUo[i] = cuv; pCLo[i] = clv; pCSo[i] = csv; }
            }

            float inv = 1.f/(cuv + ovv);
            float qu = cuv*inv, ql = csv*inv;
            float res = ob - pmu;
            float covf = 1.f - qu;
            float pu  = vld ? pmu + qu*res : pmu;
            float pl  = vld ? pml + ql*res : pml;
            float pcu = vld ? covf*cuv     : cuv;
            float pcl = vld ? clv - ql*csv : clv;
            float pcs = vld ? covf*csv     : csv;

            if (f == 0)      { sm[O_MU+3+i] = pu;  sm[O_ML+3+i]  = pl; }
            else if (f == 2)   sm[O_PCU+3+i] = pcu;
            else if (f == 4)   sm[O_PCL+3+i] = pcl;
            else if (f == 6)   sm[O_PCS+3+i] = pcs;

            float p0 = cb0q + pu*cwa0 + pl*cwb0;
            float p1 = cb1q + pu*cwa1 + pl*cwb1;
            p0 = wave_red64(p0); p1 = wave_red64(p1);
            if (i == 0) {
                sm[O_LG + k0] = p0;
                if (k1 < 15) sm[O_LG + k1] = p1;
            }
            bar_lds();   // b1

            // --- P2: out-stores (f3/f5), softmax, blend, band write ---
            if (f == 3)      { pPU[i] = pu; pPU[64+i] = pl; }
            else if (f == 5) { pP1[i] = pcu; pP2[i] = pcl; pP3[i] = pcs; }

            float4 L0 = *(const float4*)&sm[O_LG+0];
            float4 L1 = *(const float4*)&sm[O_LG+4];
            float4 L2 = *(const float4*)&sm[O_LG+8];
            float4 L3 = *(const float4*)&sm[O_LG+12];
            float lgv[15] = {L0.x,L0.y,L0.z,L0.w, L1.x,L1.y,L1.z,L1.w,
                             L2.x,L2.y,L2.z,L2.w, L3.x,L3.y,L3.z};
            // max via v_max3 tree
            float m0 = fmaxf(fmaxf(lgv[0],lgv[1]),lgv[2]);
            float m1 = fmaxf(fmaxf(lgv[3],lgv[4]),lgv[5]);
            float m2 = fmaxf(fmaxf(lgv[6],lgv[7]),lgv[8]);
            float m3 = fmaxf(fmaxf(lgv[9],lgv[10]),lgv[11]);
            float m4 = fmaxf(fmaxf(lgv[12],lgv[13]),lgv[14]);
            float mx = fmaxf(fmaxf(fmaxf(m0,m1),fmaxf(m2,m3)),m4);
            float ssum = 0.f;
            #pragma unroll
            for (int k = 0; k < 15; ++k) { lgv[k] = exp2f(lgv[k]-mx); ssum += lgv[k]; }
            float isv = 1.f/ssum;

            float bnd[4] = {0.f,0.f,0.f,0.f};
            #pragma unroll
            for (int k = 0; k < 15; ++k) {
                #pragma unroll
                for (int dd = 0; dd < 4; ++dd) bnd[dd] += lgv[k]*bas[k][dd];
            }
            #pragma unroll
            for (int dd = 0; dd < 4; ++dd) bnd[dd] *= isv;
            if (!oddw) {
                if (f == 0 || f == 6) bnd[3] += 1.f;  // +eye diag (d==3): A, D
                float4 v = {bnd[0],bnd[1],bnd[2],bnd[3]};
                *(float4*)&sm[O_BNDL + (m*64+i)*4] = v;
            } else {
                float4 v = {bnd[0],bnd[1],bnd[2],0.f};
                *(float4*)&sm[O_BNDH + (m*64+i)*4] = v;
            }
            bar_lds();   // b2

            // --- P3: role-split propagation (bands via 16B-stride b128) ---
            #define LDBAND(mm, R) { \
                float4 lo_ = *(const float4*)&sm[O_BNDL + ((mm)*64+i)*4]; \
                float4 hi_ = *(const float4*)&sm[O_BNDH + ((mm)*64+i)*4]; \
                R[0]=lo_.x; R[1]=lo_.y; R[2]=lo_.z; R[3]=lo_.w; \
                R[4]=hi_.x; R[5]=hi_.y; R[6]=hi_.z; }
            if (f == 0) {
                float A[7], Bb[7]; LDBAND(0, A); LDBAND(1, Bb);
                float acc = sm[O_CT + s*128 + i];
                #pragma unroll
                for (int d = 0; d < 7; ++d)
                    acc += A[d]*sm[O_MU+i+d] + Bb[d]*sm[O_ML+i+d];
                sm[O_PM+i] = acc;
            } else if (f == 1) {
                float Cv[7], Dv[7]; LDBAND(2, Cv); LDBAND(3, Dv);
                float acc = sm[O_CT + s*128 + 64 + i];
                #pragma unroll
                for (int d = 0; d < 7; ++d)
                    acc += Cv[d]*sm[O_MU+i+d] + Dv[d]*sm[O_ML+i+d];
                sm[O_PM+64+i] = acc;
            } else if (f == 2) {
                float A[7], Bb[7]; LDBAND(0, A); LDBAND(1, Bb);
                float acc = sm[O_TCU+i];
                #pragma unroll
                for (int d = 0; d < 7; ++d) {
                    float pux = sm[O_PCU+i+d], psx = sm[O_PCS+i+d], plx = sm[O_PCL+i+d];
                    acc += A[d]*A[d]*pux + 2.f*A[d]*Bb[d]*psx + Bb[d]*Bb[d]*plx;
                }
                sm[O_CU+i] = acc;
            } else if (f == 4) {
                float Cv[7], Dv[7]; LDBAND(2, Cv); LDBAND(3, Dv);
                float acc = sm[O_TCL+i];
                #pragma unroll
                for (int d = 0; d < 7; ++d) {
                    float pux = sm[O_PCU+i+d], psx = sm[O_PCS+i+d], plx = sm[O_PCL+i+d];
                    acc += Cv[d]*Cv[d]*pux + 2.f*Cv[d]*Dv[d]*psx + Dv[d]*Dv[d]*plx;
                }
                sm[O_CL+i] = acc;
            } else if (f == 6) {
                float A[7], Cv[7], Dv[7]; LDBAND(0, A); LDBAND(2, Cv); LDBAND(3, Dv);
                float acc = 0.f;
                #pragma unroll
                for (int d = 0; d < 7; ++d) {
                    float pux = sm[O_PCU+i+d], psx = sm[O_PCS+i+d];
                    acc += A[d]*(Cv[d]*pux + Dv[d]*psx);
                }
                sm[O_CS1+i] = acc;
            } else if (f == 7) {
                float Bb[7], Cv[7], Dv[7]; LDBAND(1, Bb); LDBAND(2, Cv); LDBAND(3, Dv);
                float acc = 0.f;
                #pragma unroll
                for (int d = 0; d < 7; ++d) {
                    float psx = sm[O_PCS+i+d], plx = sm[O_PCL+i+d];
                    acc += Bb[d]*(Cv[d]*psx + Dv[d]*plx);
                }
                sm[O_CS2+i] = acc;
            }
            #undef LDBAND

            // advance output pointers
            if (f == 3)      { pPU += 128; pNP += 128; }
            else if (f == 5) { pP1 += 64; pP2 += 64; pP3 += 64;
                               pCUo += 64; pCLo += 64; pCSo += 64; }
            bar_lds();   // b3
        }
    }

    // epilogue: deferred stores of step T-1 (pointers now at slot T-1)
    if (f == 3) {
        pNP[i]    = sm[O_PM+i];
        pNP[64+i] = sm[O_PM+64+i];
    } else if (f == 5) {
        pCUo[i] = sm[O_CU+i];
        pCLo[i] = sm[O_CL+i];
        pCSo[i] = sm[O_CS1+i] + sm[O_CS2+i];
    }
}

extern "C" void kernel_launch(void* const* d_in, const int* in_sizes, int n_in,
                              void* d_out, int out_size, void* d_ws, size_t ws_size,
                              hipStream_t stream) {
    (void)in_sizes; (void)n_in; (void)d_ws; (void)ws_size; (void)out_size;
    rkn_scan_kernel<<<B_, NT, 0, stream>>>(
        (const float*)d_in[0],  (const float*)d_in[1],  (const float*)d_in[2],
        (const float*)d_in[3],  (const float*)d_in[4],  (const float*)d_in[5],
        (const float*)d_in[6],  (const float*)d_in[7],  (const float*)d_in[8],
        (const float*)d_in[9],  (const float*)d_in[10], (const float*)d_in[11],
        (const float*)d_in[12], (const float*)d_in[13], (const int*)d_in[14],
        (float*)d_out);
}